// Round 5
// baseline (203.834 us; speedup 1.0000x reference)
//
#include <hip/hip_runtime.h>
#include <hip/hip_bf16.h>

typedef short bf16x8 __attribute__((ext_vector_type(8)));
typedef float f32x4 __attribute__((ext_vector_type(4)));

#define MFMA16(a, b, c) __builtin_amdgcn_mfma_f32_16x16x32_bf16(a, b, c, 0, 0, 0)

static constexpr int SEQ = 1024;
static constexpr int DIM = 1024;
static constexpr int NH = 16;
static constexpr int HD = 64;

#if __has_builtin(__builtin_amdgcn_rcpf)
#define FAST_RCP(x) __builtin_amdgcn_rcpf(x)
#else
#define FAST_RCP(x) (1.0f / (x))
#endif

#if __has_builtin(__builtin_amdgcn_exp2f)
#define EXP2F(x) __builtin_amdgcn_exp2f(x)
#else
#define EXP2F(x) exp2f(x)
#endif

__device__ __forceinline__ int swz(int r) { return r ^ (r >> 3); } // row-XOR bank swizzle

// ---------------------------------------------------------------------------
// fused fp32->bf16 conversion for all 5 tensors (grid.y selects region)
// ---------------------------------------------------------------------------
__global__ __launch_bounds__(256) void cvt_all(
    const float* __restrict__ x,  const float* __restrict__ wq,
    const float* __restrict__ wk, const float* __restrict__ wv,
    const float* __restrict__ wo,
    __hip_bfloat16* __restrict__ xb,  __hip_bfloat16* __restrict__ wqb,
    __hip_bfloat16* __restrict__ wkb, __hip_bfloat16* __restrict__ wvb,
    __hip_bfloat16* __restrict__ wob)
{
    const int reg = blockIdx.y;
    const float* src; __hip_bfloat16* dst; int n;
    if      (reg == 0) { src = x;  dst = xb;  n = 2 * SEQ * DIM; }
    else if (reg == 1) { src = wq; dst = wqb; n = DIM * DIM; }
    else if (reg == 2) { src = wk; dst = wkb; n = DIM * DIM; }
    else if (reg == 3) { src = wv; dst = wvb; n = DIM * DIM; }
    else               { src = wo; dst = wob; n = DIM * DIM; }
    const int i = (blockIdx.x * 256 + threadIdx.x) * 4;
    if (i < n) {
        float4 v = *(const float4*)(src + i);
        __hip_bfloat16 t[4];
        t[0] = __float2bfloat16(v.x); t[1] = __float2bfloat16(v.y);
        t[2] = __float2bfloat16(v.z); t[3] = __float2bfloat16(v.w);
        *(ushort4*)(dst + i) = *(ushort4*)t;
    }
}

// ---------------------------------------------------------------------------
// GEMM 64x128 tile, BK=32, register-staged pipelined K-loop (global->VGPR
// prefetch of iter k+1 overlaps compute of iter k), 4 waves (wave = 32x64).
// QKV: grid.z selects W/bias/Y. Y = A*W^T + bias, bf16 out.
// ---------------------------------------------------------------------------
__global__ __launch_bounds__(256) void gemm_qkv(
    const __hip_bfloat16* __restrict__ A,
    const __hip_bfloat16* __restrict__ W0, const __hip_bfloat16* __restrict__ W1,
    const __hip_bfloat16* __restrict__ W2,
    const float* __restrict__ b0, const float* __restrict__ b1,
    const float* __restrict__ b2,
    __hip_bfloat16* __restrict__ Y0, __hip_bfloat16* __restrict__ Y1,
    __hip_bfloat16* __restrict__ Y2,
    int M, int N, int K)
{
    __shared__ __align__(16) __hip_bfloat16 As[64 * 32];
    __shared__ __align__(16) __hip_bfloat16 Ws[128 * 32];

    const int z = blockIdx.z;
    const __hip_bfloat16* W = (z == 0) ? W0 : ((z == 1) ? W1 : W2);
    const float* bias = (z == 0) ? b0 : ((z == 1) ? b1 : b2);
    __hip_bfloat16* Y = (z == 0) ? Y0 : ((z == 1) ? Y1 : Y2);

    const int tid = threadIdx.x;
    const int wv = tid >> 6, lane = tid & 63;
    const int col16 = lane & 15, quad = lane >> 4;
    const int m0 = blockIdx.x * 64, n0 = blockIdx.y * 128;

    // staging chunks: A chunk = tid (256), B chunks = tid, 256+tid (512)
    const int cb1 = 256 + tid;
    const __hip_bfloat16* ga  = A + (size_t)(m0 + (tid >> 2)) * K + (tid & 3) * 8;
    const __hip_bfloat16* gb0 = W + (size_t)(n0 + (tid >> 2)) * K + (tid & 3) * 8;
    const __hip_bfloat16* gb1 = W + (size_t)(n0 + (cb1 >> 2)) * K + (cb1 & 3) * 8;

    const int wr = wv >> 1, wc = wv & 1;
    const __hip_bfloat16* ar = As + (wr * 32 + col16) * 32 + quad * 8;
    const __hip_bfloat16* br = Ws + (wc * 64 + col16) * 32 + quad * 8;

    f32x4 acc[8] = {};

    bf16x8 rA  = *(const bf16x8*)(ga);
    bf16x8 rB0 = *(const bf16x8*)(gb0);
    bf16x8 rB1 = *(const bf16x8*)(gb1);

#pragma unroll 2
    for (int k0 = 0; k0 < K; k0 += 32) {
        __syncthreads();
        *(bf16x8*)(As + (size_t)tid * 8) = rA;
        *(bf16x8*)(Ws + (size_t)tid * 8) = rB0;
        *(bf16x8*)(Ws + 2048 + (size_t)tid * 8) = rB1;
        if (k0 + 32 < K) {
            rA  = *(const bf16x8*)(ga  + k0 + 32);
            rB0 = *(const bf16x8*)(gb0 + k0 + 32);
            rB1 = *(const bf16x8*)(gb1 + k0 + 32);
        }
        __syncthreads();
        bf16x8 af[2], bfm[4];
#pragma unroll
        for (int mt = 0; mt < 2; ++mt) af[mt] = *(const bf16x8*)(ar + mt * 16 * 32);
#pragma unroll
        for (int nt = 0; nt < 4; ++nt) bfm[nt] = *(const bf16x8*)(br + nt * 16 * 32);
#pragma unroll
        for (int mt = 0; mt < 2; ++mt)
#pragma unroll
            for (int nt = 0; nt < 4; ++nt)
                acc[mt * 4 + nt] = MFMA16(af[mt], bfm[nt], acc[mt * 4 + nt]);
    }

#pragma unroll
    for (int nt = 0; nt < 4; ++nt) {
        const int n = n0 + wc * 64 + nt * 16 + col16;
        const float bv = bias[n];
#pragma unroll
        for (int mt = 0; mt < 2; ++mt) {
#pragma unroll
            for (int r = 0; r < 4; ++r) {
                const int m = m0 + wr * 32 + mt * 16 + quad * 4 + r;
                Y[(size_t)m * N + n] = __float2bfloat16(acc[mt * 4 + nt][r] + bv);
            }
        }
    }
}

// ---------------------------------------------------------------------------
// O-proj split-K=2, same register-staged pipeline. Partial 0 carries bias;
// partials summed in ln_kernel. fp32 out.
// ---------------------------------------------------------------------------
__global__ __launch_bounds__(256) void gemm_osplit(
    const __hip_bfloat16* __restrict__ A,
    const __hip_bfloat16* __restrict__ W,
    const float* __restrict__ bias,
    float* __restrict__ Y0, float* __restrict__ Y1,
    int M, int N, int K)
{
    __shared__ __align__(16) __hip_bfloat16 As[64 * 32];
    __shared__ __align__(16) __hip_bfloat16 Ws[128 * 32];

    const int z = blockIdx.z;
    float* Y = (z == 0) ? Y0 : Y1;
    const int kb = z * 512;

    const int tid = threadIdx.x;
    const int wv = tid >> 6, lane = tid & 63;
    const int col16 = lane & 15, quad = lane >> 4;
    const int m0 = blockIdx.x * 64, n0 = blockIdx.y * 128;

    const int cb1 = 256 + tid;
    const __hip_bfloat16* ga  = A + (size_t)(m0 + (tid >> 2)) * K + (tid & 3) * 8 + kb;
    const __hip_bfloat16* gb0 = W + (size_t)(n0 + (tid >> 2)) * K + (tid & 3) * 8 + kb;
    const __hip_bfloat16* gb1 = W + (size_t)(n0 + (cb1 >> 2)) * K + (cb1 & 3) * 8 + kb;

    const int wr = wv >> 1, wc = wv & 1;
    const __hip_bfloat16* ar = As + (wr * 32 + col16) * 32 + quad * 8;
    const __hip_bfloat16* br = Ws + (wc * 64 + col16) * 32 + quad * 8;

    f32x4 acc[8] = {};

    bf16x8 rA  = *(const bf16x8*)(ga);
    bf16x8 rB0 = *(const bf16x8*)(gb0);
    bf16x8 rB1 = *(const bf16x8*)(gb1);

#pragma unroll 2
    for (int k0 = 0; k0 < 512; k0 += 32) {
        __syncthreads();
        *(bf16x8*)(As + (size_t)tid * 8) = rA;
        *(bf16x8*)(Ws + (size_t)tid * 8) = rB0;
        *(bf16x8*)(Ws + 2048 + (size_t)tid * 8) = rB1;
        if (k0 + 32 < 512) {
            rA  = *(const bf16x8*)(ga  + k0 + 32);
            rB0 = *(const bf16x8*)(gb0 + k0 + 32);
            rB1 = *(const bf16x8*)(gb1 + k0 + 32);
        }
        __syncthreads();
        bf16x8 af[2], bfm[4];
#pragma unroll
        for (int mt = 0; mt < 2; ++mt) af[mt] = *(const bf16x8*)(ar + mt * 16 * 32);
#pragma unroll
        for (int nt = 0; nt < 4; ++nt) bfm[nt] = *(const bf16x8*)(br + nt * 16 * 32);
#pragma unroll
        for (int mt = 0; mt < 2; ++mt)
#pragma unroll
            for (int nt = 0; nt < 4; ++nt)
                acc[mt * 4 + nt] = MFMA16(af[mt], bfm[nt], acc[mt * 4 + nt]);
    }

#pragma unroll
    for (int nt = 0; nt < 4; ++nt) {
        const int n = n0 + wc * 64 + nt * 16 + col16;
        const float bv = (z == 0) ? bias[n] : 0.0f;
#pragma unroll
        for (int mt = 0; mt < 2; ++mt) {
#pragma unroll
            for (int r = 0; r < 4; ++r) {
                const int m = m0 + wr * 32 + mt * 16 + quad * 4 + r;
                Y[(size_t)m * N + n] = acc[mt * 4 + nt][r] + bv;
            }
        }
    }
}

// ---------------------------------------------------------------------------
// Attention. Block = 4 waves over 32 q-rows of one (b,h); wave w: row-group
// g=w&1, j-half = w>>1 (512 js each). The 5-frequency sin transform is
// collapsed into ONE degree-7 polynomial in s (angle-sum + Taylor; |c_f*s|
// <~0.6 rad -> err ~3e-7), log2e folded: w = rcp(1+exp2(-poly(s))).
// K and V fragments prefetched one j64-iter ahead (full unroll).
// ---------------------------------------------------------------------------
__global__ __launch_bounds__(256, 4) void attn_kernel(
    const __hip_bfloat16* __restrict__ Q,
    const __hip_bfloat16* __restrict__ K,
    const __hip_bfloat16* __restrict__ V,
    const float* __restrict__ alpha, const float* __restrict__ phi,
    const float* __restrict__ temperature,
    __hip_bfloat16* __restrict__ AO)
{
    __shared__ __align__(16) char smem[18432 + 5120];
    __hip_bfloat16* VtBase = (__hip_bfloat16*)smem;
    __hip_bfloat16* PlBase = (__hip_bfloat16*)(smem + 18432);
    float* Ocomb = (float*)smem;                 // [2][16][68]
    float* Dl    = (float*)(smem + 2 * 16 * 68 * 4);

    const int tid = threadIdx.x;
    const int wv = tid >> 6, lane = tid & 63;
    const int col16 = lane & 15, quad = lane >> 4;
    const int g = wv & 1, half = wv >> 1;

    const int bh = blockIdx.y, b = bh >> 4, h = bh & 15;
    const int i0 = blockIdx.x * 32 + g * 16;
    const size_t base = ((size_t)b * SEQ) * DIM + (size_t)h * HD;

    const float tempv = fabsf(temperature[0]) + 0.1f;
    const float simscale = 1.0f / (8.0f * tempv);
    const float freqs[5] = {31.0f, 37.0f, 41.0f, 43.0f, 47.0f};

    // Build degree-7 polynomial p[0..7] for scores(s)*log2e
    float p[8] = {0.f, 0.f, 0.f, 0.f, 0.f, 0.f, 0.f, 0.f};
#pragma unroll
    for (int f = 0; f < 5; ++f) {
        const float a  = alpha[h * 5 + f] * 1.44269504089f;  // fold log2(e)
        const float ph = phi[h * 5 + f];
        const float sp = __sinf(ph), cp = __cosf(ph);
        const float c  = 6.28318530718f * simscale / freqs[f];
        const float c2 = c * c, c3 = c2 * c, c4 = c2 * c2;
        const float c5 = c4 * c, c6 = c4 * c2, c7 = c4 * c3;
        p[0] += a * sp;
        p[1] += a * cp * c;
        p[2] -= a * sp * c2 * 0.5f;
        p[3] -= a * cp * c3 * (1.0f / 6.0f);
        p[4] += a * sp * c4 * (1.0f / 24.0f);
        p[5] += a * cp * c5 * (1.0f / 120.0f);
        p[6] -= a * sp * c6 * (1.0f / 720.0f);
        p[7] -= a * cp * c7 * (1.0f / 5040.0f);
    }

    const __hip_bfloat16* qrow = Q + base + (size_t)(i0 + col16) * DIM + quad * 8;
    const bf16x8 qa0 = *(const bf16x8*)(qrow);
    const bf16x8 qa1 = *(const bf16x8*)(qrow + 32);

    const __hip_bfloat16* kbase = K + base + (size_t)col16 * DIM + quad * 8;

    // Vt staging: 128 threads per half; thread: 8 d-rows x 2 j-pairs x 2 blocks
    const int tl = tid & 127;
    const int sc0 = (tl & 7) * 8;
    const int sx  = tl & 7;
    const int jj0 = (tl >> 3) * 2;
    __hip_bfloat16* VtH = VtBase + half * 64 * 72;
    __hip_bfloat16* rowp[8];
#pragma unroll
    for (int e = 0; e < 8; ++e) rowp[e] = VtH + (sc0 + (e ^ sx)) * 72;

    const __hip_bfloat16* vrd[4];
#pragma unroll
    for (int t = 0; t < 4; ++t)
        vrd[t] = VtH + swz(t * 16 + col16) * 72 + quad * 8;

    __hip_bfloat16* PlW = PlBase + wv * 16 * 40;
    const __hip_bfloat16* plr = PlW + swz(col16) * 40 + quad * 8;
    __hip_bfloat16* plw[4];
#pragma unroll
    for (int r = 0; r < 4; ++r) plw[r] = PlW + swz(quad * 4 + r) * 40;

    f32x4 o[4] = {};
    float denom[4] = {0.f, 0.f, 0.f, 0.f};

    const int jbase = half * 512;

    // prefetch iter 0
    bf16x8 va[2], vb2[2], kf[4][2];
#pragma unroll
    for (int s = 0; s < 2; ++s) {
        const __hip_bfloat16* vp = V + base + (size_t)(jbase + jj0 + 32 * s) * DIM + sc0;
        va[s] = *(const bf16x8*)(vp);
        vb2[s] = *(const bf16x8*)(vp + DIM);
    }
#pragma unroll
    for (int u = 0; u < 4; ++u) {
        const __hip_bfloat16* kp = kbase + (size_t)(jbase + u * 16) * DIM;
        kf[u][0] = *(const bf16x8*)(kp);
        kf[u][1] = *(const bf16x8*)(kp + 32);
    }

#pragma unroll
    for (int it = 0; it < 8; ++it) {
        const int j0 = jbase + it * 64;
        __syncthreads();
        // write current V tile (transposed, swizzled) to LDS
#pragma unroll
        for (int s = 0; s < 2; ++s) {
#pragma unroll
            for (int e = 0; e < 8; ++e) {
                unsigned pk = ((unsigned)(unsigned short)va[s][e]) |
                              (((unsigned)(unsigned short)vb2[s][e]) << 16);
                *(unsigned*)(rowp[e] + jj0 + 32 * s) = pk;
            }
        }
        // prefetch next iter's V and K (latency hidden behind compute)
        bf16x8 nva[2], nvb2[2], nkf[4][2];
        if (it < 7) {
            const int jn = j0 + 64;
#pragma unroll
            for (int s = 0; s < 2; ++s) {
                const __hip_bfloat16* vp = V + base + (size_t)(jn + jj0 + 32 * s) * DIM + sc0;
                nva[s] = *(const bf16x8*)(vp);
                nvb2[s] = *(const bf16x8*)(vp + DIM);
            }
#pragma unroll
            for (int u = 0; u < 4; ++u) {
                const __hip_bfloat16* kp = kbase + (size_t)(jn + u * 16) * DIM;
                nkf[u][0] = *(const bf16x8*)(kp);
                nkf[u][1] = *(const bf16x8*)(kp + 32);
            }
        }
        __syncthreads();

#pragma unroll
        for (int sub = 0; sub < 2; ++sub) {
#pragma unroll
            for (int s2 = 0; s2 < 2; ++s2) {
                const int u = sub * 2 + s2;
                f32x4 sa = {};
                sa = MFMA16(qa0, kf[u][0], sa);
                sa = MFMA16(qa1, kf[u][1], sa);
#pragma unroll
                for (int r = 0; r < 4; ++r) {
                    const float sv = sa[r];
                    float sc = fmaf(sv, p[7], p[6]);
                    sc = fmaf(sv, sc, p[5]);
                    sc = fmaf(sv, sc, p[4]);
                    sc = fmaf(sv, sc, p[3]);
                    sc = fmaf(sv, sc, p[2]);
                    sc = fmaf(sv, sc, p[1]);
                    sc = fmaf(sv, sc, p[0]);
                    const float w = FAST_RCP(1.0f + EXP2F(-sc));
                    denom[r] += w;
                    plw[r][s2 * 16 + col16] = __float2bfloat16(w);
                }
            }
            bf16x8 pa = *(const bf16x8*)plr;
#pragma unroll
            for (int t = 0; t < 4; ++t) {
                bf16x8 vb = *(const bf16x8*)(vrd[t] + 32 * sub);
                o[t] = MFMA16(pa, vb, o[t]);
            }
        }

        if (it < 7) {
#pragma unroll
            for (int s = 0; s < 2; ++s) { va[s] = nva[s]; vb2[s] = nvb2[s]; }
#pragma unroll
            for (int u = 0; u < 4; ++u) { kf[u][0] = nkf[u][0]; kf[u][1] = nkf[u][1]; }
        }
    }

#pragma unroll
    for (int r = 0; r < 4; ++r) {
        float d = denom[r];
        d += __shfl_xor(d, 1);
        d += __shfl_xor(d, 2);
        d += __shfl_xor(d, 4);
        d += __shfl_xor(d, 8);
        denom[r] = d;
    }

    __syncthreads();
    if (half == 1) {
#pragma unroll
        for (int t = 0; t < 4; ++t)
#pragma unroll
            for (int r = 0; r < 4; ++r)
                Ocomb[(g * 16 + quad * 4 + r) * 68 + t * 16 + col16] = o[t][r];
        if (col16 == 0) {
#pragma unroll
            for (int r = 0; r < 4; ++r) Dl[g * 16 + quad * 4 + r] = denom[r];
        }
    }
    __syncthreads();
    if (half == 0) {
#pragma unroll
        for (int r = 0; r < 4; ++r)
            denom[r] = denom[r] + Dl[g * 16 + quad * 4 + r] + 1e-10f;
#pragma unroll
        for (int t = 0; t < 4; ++t) {
#pragma unroll
            for (int r = 0; r < 4; ++r) {
                const float val =
                    (o[t][r] + Ocomb[(g * 16 + quad * 4 + r) * 68 + t * 16 + col16]) / denom[r];
                const size_t row = (size_t)b * SEQ + i0 + quad * 4 + r;
                AO[row * DIM + h * HD + t * 16 + col16] = __float2bfloat16(val);
            }
        }
    }
}

// ---------------------------------------------------------------------------
// LayerNorm over last dim (1024), sums the two split-K partials of O-proj.
// ---------------------------------------------------------------------------
__global__ __launch_bounds__(256) void ln_kernel(
    const float* __restrict__ Yp0,
    const float* __restrict__ Yp1,
    const float* __restrict__ gamma,
    const float* __restrict__ beta,
    float* __restrict__ out)
{
    const int row = blockIdx.x;
    const float* y0 = Yp0 + (size_t)row * DIM;
    const float* y1 = Yp1 + (size_t)row * DIM;

    float v[4];
    float s = 0.f, s2 = 0.f;
#pragma unroll
    for (int e = 0; e < 4; ++e) {
        const int idx = threadIdx.x + e * 256;
        v[e] = y0[idx] + y1[idx];
        s += v[e];
        s2 += v[e] * v[e];
    }
#pragma unroll
    for (int off = 1; off < 64; off <<= 1) {
        s  += __shfl_xor(s, off);
        s2 += __shfl_xor(s2, off);
    }
    __shared__ float ps[4], ps2[4];
    const int wave = threadIdx.x >> 6;
    if ((threadIdx.x & 63) == 0) { ps[wave] = s; ps2[wave] = s2; }
    __syncthreads();
    s  = ps[0] + ps[1] + ps[2] + ps[3];
    s2 = ps2[0] + ps2[1] + ps2[2] + ps2[3];

    const float mu   = s * (1.0f / DIM);
    const float var  = s2 * (1.0f / DIM) - mu * mu;
    const float rstd = rsqrtf(var + 1e-5f);

#pragma unroll
    for (int e = 0; e < 4; ++e) {
        const int idx = threadIdx.x + e * 256;
        out[(size_t)row * DIM + idx] =
            (v[e] - mu) * rstd * gamma[idx] + beta[idx];
    }
}

// ---------------------------------------------------------------------------
extern "C" void kernel_launch(void* const* d_in, const int* in_sizes, int n_in,
                              void* d_out, int out_size, void* d_ws, size_t ws_size,
                              hipStream_t stream)
{
    const float* x     = (const float*)d_in[0];
    const float* Wq    = (const float*)d_in[1];
    const float* bq    = (const float*)d_in[2];
    const float* Wk    = (const float*)d_in[3];
    const float* bk    = (const float*)d_in[4];
    const float* Wv    = (const float*)d_in[5];
    const float* bv    = (const float*)d_in[6];
    const float* Wo    = (const float*)d_in[7];
    const float* bo    = (const float*)d_in[8];
    const float* alpha = (const float*)d_in[9];
    const float* phi   = (const float*)d_in[10];
    const float* temp  = (const float*)d_in[11];
    const float* gamma = (const float*)d_in[12];
    const float* beta  = (const float*)d_in[13];

    float* out = (float*)d_out;

    const int B = 2;
    const int M = B * SEQ;                 // 2048

    // ws layout (MB):
    //   [0,4)   xb    [4,6) Wqb   [6,8) Wkb   [8,10) Wvb   [10,12) Wob
    //   [12,16) Qb    [16,20) Kb  [20,24) Vb  [24,28) AO
    //   Yp0 (fp32 8MB) aliases [0,8)  — xb/Wqb/Wkb dead by O-proj
    //   Yp1 (fp32 8MB) aliases [12,20) — Qb/Kb dead by O-proj
    char* wsb = (char*)d_ws;
    __hip_bfloat16* xb  = (__hip_bfloat16*)(wsb + 0);
    __hip_bfloat16* Wqb = (__hip_bfloat16*)(wsb + (4u  << 20));
    __hip_bfloat16* Wkb = (__hip_bfloat16*)(wsb + (6u  << 20));
    __hip_bfloat16* Wvb = (__hip_bfloat16*)(wsb + (8u  << 20));
    __hip_bfloat16* Wob = (__hip_bfloat16*)(wsb + (10u << 20));
    __hip_bfloat16* Qb  = (__hip_bfloat16*)(wsb + (12u << 20));
    __hip_bfloat16* Kb  = (__hip_bfloat16*)(wsb + (16u << 20));
    __hip_bfloat16* Vb  = (__hip_bfloat16*)(wsb + (20u << 20));
    __hip_bfloat16* AO  = (__hip_bfloat16*)(wsb + (24u << 20));
    float*          Yp0 = (float*)(wsb + 0);
    float*          Yp1 = (float*)(wsb + (12u << 20));

    hipLaunchKernelGGL(cvt_all, dim3(2048, 5), dim3(256), 0, stream,
                       x, Wq, Wk, Wv, Wo, xb, Wqb, Wkb, Wvb, Wob);

    hipLaunchKernelGGL(gemm_qkv, dim3(M / 64, DIM / 128, 3), dim3(256), 0, stream,
                       xb, Wqb, Wkb, Wvb, bq, bk, bv, Qb, Kb, Vb, M, DIM, DIM);

    hipLaunchKernelGGL(attn_kernel, dim3(SEQ / 32, B * NH), dim3(256), 0, stream,
                       Qb, Kb, Vb, alpha, phi, temp, AO);

    hipLaunchKernelGGL(gemm_osplit, dim3(M / 64, DIM / 128, 2), dim3(256), 0, stream,
                       AO, Wob, bo, Yp0, Yp1, M, DIM, DIM);

    hipLaunchKernelGGL(ln_kernel, dim3(M), dim3(256), 0, stream,
                       Yp0, Yp1, gamma, beta, out);
}

// Round 8
// 176.249 us; speedup vs baseline: 1.1565x; 1.1565x over previous
//
#include <hip/hip_runtime.h>
#include <hip/hip_bf16.h>

typedef short bf16x8 __attribute__((ext_vector_type(8)));
typedef float f32x4 __attribute__((ext_vector_type(4)));

#define MFMA16(a, b, c) __builtin_amdgcn_mfma_f32_16x16x32_bf16(a, b, c, 0, 0, 0)

static constexpr int SEQ = 1024;
static constexpr int DIM = 1024;
static constexpr int NH = 16;
static constexpr int HD = 64;

#if __has_builtin(__builtin_amdgcn_rcpf)
#define FAST_RCP(x) __builtin_amdgcn_rcpf(x)
#else
#define FAST_RCP(x) (1.0f / (x))
#endif

#if __has_builtin(__builtin_amdgcn_exp2f)
#define EXP2F(x) __builtin_amdgcn_exp2f(x)
#else
#define EXP2F(x) exp2f(x)
#endif

__device__ __forceinline__ int swz(int r) { return r ^ (r >> 3); } // row-XOR bank swizzle

// ---------------------------------------------------------------------------
// fused fp32->bf16 conversion for all 5 tensors (grid.y selects region)
// ---------------------------------------------------------------------------
__global__ __launch_bounds__(256) void cvt_all(
    const float* __restrict__ x,  const float* __restrict__ wq,
    const float* __restrict__ wk, const float* __restrict__ wv,
    const float* __restrict__ wo,
    __hip_bfloat16* __restrict__ xb,  __hip_bfloat16* __restrict__ wqb,
    __hip_bfloat16* __restrict__ wkb, __hip_bfloat16* __restrict__ wvb,
    __hip_bfloat16* __restrict__ wob)
{
    const int reg = blockIdx.y;
    const float* src; __hip_bfloat16* dst; int n;
    if      (reg == 0) { src = x;  dst = xb;  n = 2 * SEQ * DIM; }
    else if (reg == 1) { src = wq; dst = wqb; n = DIM * DIM; }
    else if (reg == 2) { src = wk; dst = wkb; n = DIM * DIM; }
    else if (reg == 3) { src = wv; dst = wvb; n = DIM * DIM; }
    else               { src = wo; dst = wob; n = DIM * DIM; }
    const int i = (blockIdx.x * 256 + threadIdx.x) * 4;
    if (i < n) {
        float4 v = *(const float4*)(src + i);
        __hip_bfloat16 t[4];
        t[0] = __float2bfloat16(v.x); t[1] = __float2bfloat16(v.y);
        t[2] = __float2bfloat16(v.z); t[3] = __float2bfloat16(v.w);
        *(ushort4*)(dst + i) = *(ushort4*)t;
    }
}

// ---------------------------------------------------------------------------
// GEMM 64x128 tile, BK=32, register-staged pipelined K-loop.
// QKV: grid.z selects W/bias/Y. Y = A*W^T + bias, bf16 out.
// ---------------------------------------------------------------------------
__global__ __launch_bounds__(256) void gemm_qkv(
    const __hip_bfloat16* __restrict__ A,
    const __hip_bfloat16* __restrict__ W0, const __hip_bfloat16* __restrict__ W1,
    const __hip_bfloat16* __restrict__ W2,
    const float* __restrict__ b0, const float* __restrict__ b1,
    const float* __restrict__ b2,
    __hip_bfloat16* __restrict__ Y0, __hip_bfloat16* __restrict__ Y1,
    __hip_bfloat16* __restrict__ Y2,
    int M, int N, int K)
{
    __shared__ __align__(16) __hip_bfloat16 As[64 * 32];
    __shared__ __align__(16) __hip_bfloat16 Ws[128 * 32];

    const int z = blockIdx.z;
    const __hip_bfloat16* W = (z == 0) ? W0 : ((z == 1) ? W1 : W2);
    const float* bias = (z == 0) ? b0 : ((z == 1) ? b1 : b2);
    __hip_bfloat16* Y = (z == 0) ? Y0 : ((z == 1) ? Y1 : Y2);

    const int tid = threadIdx.x;
    const int wv = tid >> 6, lane = tid & 63;
    const int col16 = lane & 15, quad = lane >> 4;
    const int m0 = blockIdx.x * 64, n0 = blockIdx.y * 128;

    const int cb1 = 256 + tid;
    const __hip_bfloat16* ga  = A + (size_t)(m0 + (tid >> 2)) * K + (tid & 3) * 8;
    const __hip_bfloat16* gb0 = W + (size_t)(n0 + (tid >> 2)) * K + (tid & 3) * 8;
    const __hip_bfloat16* gb1 = W + (size_t)(n0 + (cb1 >> 2)) * K + (cb1 & 3) * 8;

    const int wr = wv >> 1, wc = wv & 1;
    const __hip_bfloat16* ar = As + (wr * 32 + col16) * 32 + quad * 8;
    const __hip_bfloat16* br = Ws + (wc * 64 + col16) * 32 + quad * 8;

    f32x4 acc[8] = {};

    bf16x8 rA  = *(const bf16x8*)(ga);
    bf16x8 rB0 = *(const bf16x8*)(gb0);
    bf16x8 rB1 = *(const bf16x8*)(gb1);

#pragma unroll 2
    for (int k0 = 0; k0 < K; k0 += 32) {
        __syncthreads();
        *(bf16x8*)(As + (size_t)tid * 8) = rA;
        *(bf16x8*)(Ws + (size_t)tid * 8) = rB0;
        *(bf16x8*)(Ws + 2048 + (size_t)tid * 8) = rB1;
        if (k0 + 32 < K) {
            rA  = *(const bf16x8*)(ga  + k0 + 32);
            rB0 = *(const bf16x8*)(gb0 + k0 + 32);
            rB1 = *(const bf16x8*)(gb1 + k0 + 32);
        }
        __syncthreads();
        bf16x8 af[2], bfm[4];
#pragma unroll
        for (int mt = 0; mt < 2; ++mt) af[mt] = *(const bf16x8*)(ar + mt * 16 * 32);
#pragma unroll
        for (int nt = 0; nt < 4; ++nt) bfm[nt] = *(const bf16x8*)(br + nt * 16 * 32);
#pragma unroll
        for (int mt = 0; mt < 2; ++mt)
#pragma unroll
            for (int nt = 0; nt < 4; ++nt)
                acc[mt * 4 + nt] = MFMA16(af[mt], bfm[nt], acc[mt * 4 + nt]);
    }

#pragma unroll
    for (int nt = 0; nt < 4; ++nt) {
        const int n = n0 + wc * 64 + nt * 16 + col16;
        const float bv = bias[n];
#pragma unroll
        for (int mt = 0; mt < 2; ++mt) {
#pragma unroll
            for (int r = 0; r < 4; ++r) {
                const int m = m0 + wr * 32 + mt * 16 + quad * 4 + r;
                Y[(size_t)m * N + n] = __float2bfloat16(acc[mt * 4 + nt][r] + bv);
            }
        }
    }
}

// ---------------------------------------------------------------------------
// O-proj split-K=2, register-staged. Partial 0 carries bias; summed in ln.
// ---------------------------------------------------------------------------
__global__ __launch_bounds__(256) void gemm_osplit(
    const __hip_bfloat16* __restrict__ A,
    const __hip_bfloat16* __restrict__ W,
    const float* __restrict__ bias,
    float* __restrict__ Y0, float* __restrict__ Y1,
    int M, int N, int K)
{
    __shared__ __align__(16) __hip_bfloat16 As[64 * 32];
    __shared__ __align__(16) __hip_bfloat16 Ws[128 * 32];

    const int z = blockIdx.z;
    float* Y = (z == 0) ? Y0 : Y1;
    const int kb = z * 512;

    const int tid = threadIdx.x;
    const int wv = tid >> 6, lane = tid & 63;
    const int col16 = lane & 15, quad = lane >> 4;
    const int m0 = blockIdx.x * 64, n0 = blockIdx.y * 128;

    const int cb1 = 256 + tid;
    const __hip_bfloat16* ga  = A + (size_t)(m0 + (tid >> 2)) * K + (tid & 3) * 8 + kb;
    const __hip_bfloat16* gb0 = W + (size_t)(n0 + (tid >> 2)) * K + (tid & 3) * 8 + kb;
    const __hip_bfloat16* gb1 = W + (size_t)(n0 + (cb1 >> 2)) * K + (cb1 & 3) * 8 + kb;

    const int wr = wv >> 1, wc = wv & 1;
    const __hip_bfloat16* ar = As + (wr * 32 + col16) * 32 + quad * 8;
    const __hip_bfloat16* br = Ws + (wc * 64 + col16) * 32 + quad * 8;

    f32x4 acc[8] = {};

    bf16x8 rA  = *(const bf16x8*)(ga);
    bf16x8 rB0 = *(const bf16x8*)(gb0);
    bf16x8 rB1 = *(const bf16x8*)(gb1);

#pragma unroll 2
    for (int k0 = 0; k0 < 512; k0 += 32) {
        __syncthreads();
        *(bf16x8*)(As + (size_t)tid * 8) = rA;
        *(bf16x8*)(Ws + (size_t)tid * 8) = rB0;
        *(bf16x8*)(Ws + 2048 + (size_t)tid * 8) = rB1;
        if (k0 + 32 < 512) {
            rA  = *(const bf16x8*)(ga  + k0 + 32);
            rB0 = *(const bf16x8*)(gb0 + k0 + 32);
            rB1 = *(const bf16x8*)(gb1 + k0 + 32);
        }
        __syncthreads();
        bf16x8 af[2], bfm[4];
#pragma unroll
        for (int mt = 0; mt < 2; ++mt) af[mt] = *(const bf16x8*)(ar + mt * 16 * 32);
#pragma unroll
        for (int nt = 0; nt < 4; ++nt) bfm[nt] = *(const bf16x8*)(br + nt * 16 * 32);
#pragma unroll
        for (int mt = 0; mt < 2; ++mt)
#pragma unroll
            for (int nt = 0; nt < 4; ++nt)
                acc[mt * 4 + nt] = MFMA16(af[mt], bfm[nt], acc[mt * 4 + nt]);
    }

#pragma unroll
    for (int nt = 0; nt < 4; ++nt) {
        const int n = n0 + wc * 64 + nt * 16 + col16;
        const float bv = (z == 0) ? bias[n] : 0.0f;
#pragma unroll
        for (int mt = 0; mt < 2; ++mt) {
#pragma unroll
            for (int r = 0; r < 4; ++r) {
                const int m = m0 + wr * 32 + mt * 16 + quad * 4 + r;
                Y[(size_t)m * N + n] = acc[mt * 4 + nt][r] + bv;
            }
        }
    }
}

// ---------------------------------------------------------------------------
// Attention — EXACT R4 structure (last passing fast version, 51.5us) with the
// sin-sum transform replaced by the R5-validated degree-7 polynomial.
// Block = 256 thr = 4 waves over 32 q-rows of one (b,h):
//   wave w: row-group g=w&1 (16 rows), j-half = w>>1 (512 js each).
// Per j64-iter: stage transposed V (row-swizzled), preload all K-frags,
// QK^T MFMA -> poly(s) -> sigmoid via exp2 -> Pl (row-swizzled) -> PV MFMA.
// Halves combined via LDS at end. No launch_bounds clamp, no next-iter
// register double-buffer (those caused the R5 spill regression).
// ---------------------------------------------------------------------------
__global__ __launch_bounds__(256) void attn_kernel(
    const __hip_bfloat16* __restrict__ Q,
    const __hip_bfloat16* __restrict__ K,
    const __hip_bfloat16* __restrict__ V,
    const float* __restrict__ alpha, const float* __restrict__ phi,
    const float* __restrict__ temperature,
    __hip_bfloat16* __restrict__ AO)
{
    __shared__ __align__(16) char smem[18432 + 5120];
    __hip_bfloat16* VtBase = (__hip_bfloat16*)smem;
    __hip_bfloat16* PlBase = (__hip_bfloat16*)(smem + 18432);
    float* Ocomb = (float*)smem;                 // [2][16][68]
    float* Dl    = (float*)(smem + 2 * 16 * 68 * 4);

    const int tid = threadIdx.x;
    const int wv = tid >> 6, lane = tid & 63;
    const int col16 = lane & 15, quad = lane >> 4;
    const int g = wv & 1, half = wv >> 1;

    const int bh = blockIdx.y, b = bh >> 4, h = bh & 15;
    const int i0 = blockIdx.x * 32 + g * 16;
    const size_t base = ((size_t)b * SEQ) * DIM + (size_t)h * HD;

    const float tempv = fabsf(temperature[0]) + 0.1f;
    const float simscale = 1.0f / (8.0f * tempv);
    const float freqs[5] = {31.0f, 37.0f, 41.0f, 43.0f, 47.0f};

    // degree-7 poly of log2e*score(s); w = rcp(1+exp2(-poly(s)))  [R5-validated]
    float p[8] = {0.f, 0.f, 0.f, 0.f, 0.f, 0.f, 0.f, 0.f};
#pragma unroll
    for (int f = 0; f < 5; ++f) {
        const float a  = alpha[h * 5 + f] * 1.44269504089f;  // fold log2(e)
        const float ph = phi[h * 5 + f];
        const float sp = __sinf(ph), cp = __cosf(ph);
        const float c  = 6.28318530718f * simscale / freqs[f];
        const float c2 = c * c, c3 = c2 * c, c4 = c2 * c2;
        const float c5 = c4 * c, c6 = c4 * c2, c7 = c4 * c3;
        p[0] += a * sp;
        p[1] += a * cp * c;
        p[2] -= a * sp * c2 * 0.5f;
        p[3] -= a * cp * c3 * (1.0f / 6.0f);
        p[4] += a * sp * c4 * (1.0f / 24.0f);
        p[5] += a * cp * c5 * (1.0f / 120.0f);
        p[6] -= a * sp * c6 * (1.0f / 720.0f);
        p[7] -= a * cp * c7 * (1.0f / 5040.0f);
    }

    const __hip_bfloat16* qrow = Q + base + (size_t)(i0 + col16) * DIM + quad * 8;
    const bf16x8 qa0 = *(const bf16x8*)(qrow);
    const bf16x8 qa1 = *(const bf16x8*)(qrow + 32);

    const __hip_bfloat16* kbase = K + base + (size_t)col16 * DIM + quad * 8;

    // Vt staging: 128 threads per half; thread: 8 d-rows x 2 j-pairs x 2 blocks
    const int tl = tid & 127;
    const int sc0 = (tl & 7) * 8;
    const int sx  = tl & 7;
    const int jj0 = (tl >> 3) * 2;
    __hip_bfloat16* VtH = VtBase + half * 64 * 72;
    __hip_bfloat16* rowp[8];
#pragma unroll
    for (int e = 0; e < 8; ++e) rowp[e] = VtH + (sc0 + (e ^ sx)) * 72;

    const __hip_bfloat16* vrd[4];
#pragma unroll
    for (int t = 0; t < 4; ++t)
        vrd[t] = VtH + swz(t * 16 + col16) * 72 + quad * 8;

    __hip_bfloat16* PlW = PlBase + wv * 16 * 40;
    const __hip_bfloat16* plr = PlW + swz(col16) * 40 + quad * 8;
    __hip_bfloat16* plw[4];
#pragma unroll
    for (int r = 0; r < 4; ++r) plw[r] = PlW + swz(quad * 4 + r) * 40;

    f32x4 o[4] = {};
    float denom[4] = {0.f, 0.f, 0.f, 0.f};

    for (int it = 0; it < 8; ++it) {
        const int j0 = half * 512 + it * 64;
        __syncthreads();
#pragma unroll
        for (int s = 0; s < 2; ++s) {
            const __hip_bfloat16* vp = V + base + (size_t)(j0 + jj0 + 32 * s) * DIM + sc0;
            bf16x8 va  = *(const bf16x8*)(vp);
            bf16x8 vb2 = *(const bf16x8*)(vp + DIM);
#pragma unroll
            for (int e = 0; e < 8; ++e) {
                unsigned pk = ((unsigned)(unsigned short)va[e]) |
                              (((unsigned)(unsigned short)vb2[e]) << 16);
                *(unsigned*)(rowp[e] + jj0 + 32 * s) = pk;
            }
        }
        // preload ALL K fragments for this j64 before the transform loops
        bf16x8 kf[4][2];
#pragma unroll
        for (int u = 0; u < 4; ++u) {
            const __hip_bfloat16* kp = kbase + (size_t)(j0 + u * 16) * DIM;
            kf[u][0] = *(const bf16x8*)(kp);
            kf[u][1] = *(const bf16x8*)(kp + 32);
        }
        __syncthreads();

#pragma unroll
        for (int sub = 0; sub < 2; ++sub) {
#pragma unroll
            for (int s2 = 0; s2 < 2; ++s2) {
                const int u = sub * 2 + s2;
                f32x4 sa = {};
                sa = MFMA16(qa0, kf[u][0], sa);
                sa = MFMA16(qa1, kf[u][1], sa);
#pragma unroll
                for (int r = 0; r < 4; ++r) {
                    const float sv = sa[r];
                    float sc = fmaf(sv, p[7], p[6]);
                    sc = fmaf(sv, sc, p[5]);
                    sc = fmaf(sv, sc, p[4]);
                    sc = fmaf(sv, sc, p[3]);
                    sc = fmaf(sv, sc, p[2]);
                    sc = fmaf(sv, sc, p[1]);
                    sc = fmaf(sv, sc, p[0]);
                    const float w = FAST_RCP(1.0f + EXP2F(-sc));
                    denom[r] += w;
                    plw[r][s2 * 16 + col16] = __float2bfloat16(w);
                }
            }
            bf16x8 pa = *(const bf16x8*)plr;
#pragma unroll
            for (int t = 0; t < 4; ++t) {
                bf16x8 vb = *(const bf16x8*)(vrd[t] + 32 * sub);
                o[t] = MFMA16(pa, vb, o[t]);
            }
        }
    }

#pragma unroll
    for (int r = 0; r < 4; ++r) {
        float d = denom[r];
        d += __shfl_xor(d, 1);
        d += __shfl_xor(d, 2);
        d += __shfl_xor(d, 4);
        d += __shfl_xor(d, 8);
        denom[r] = d;
    }

    __syncthreads();
    if (half == 1) {
#pragma unroll
        for (int t = 0; t < 4; ++t)
#pragma unroll
            for (int r = 0; r < 4; ++r)
                Ocomb[(g * 16 + quad * 4 + r) * 68 + t * 16 + col16] = o[t][r];
        if (col16 == 0) {
#pragma unroll
            for (int r = 0; r < 4; ++r) Dl[g * 16 + quad * 4 + r] = denom[r];
        }
    }
    __syncthreads();
    if (half == 0) {
#pragma unroll
        for (int r = 0; r < 4; ++r)
            denom[r] = denom[r] + Dl[g * 16 + quad * 4 + r] + 1e-10f;
#pragma unroll
        for (int t = 0; t < 4; ++t) {
#pragma unroll
            for (int r = 0; r < 4; ++r) {
                const float val =
                    (o[t][r] + Ocomb[(g * 16 + quad * 4 + r) * 68 + t * 16 + col16]) / denom[r];
                const size_t row = (size_t)b * SEQ + i0 + quad * 4 + r;
                AO[row * DIM + h * HD + t * 16 + col16] = __float2bfloat16(val);
            }
        }
    }
}

// ---------------------------------------------------------------------------
// LayerNorm over last dim (1024), sums the two split-K partials of O-proj.
// ---------------------------------------------------------------------------
__global__ __launch_bounds__(256) void ln_kernel(
    const float* __restrict__ Yp0,
    const float* __restrict__ Yp1,
    const float* __restrict__ gamma,
    const float* __restrict__ beta,
    float* __restrict__ out)
{
    const int row = blockIdx.x;
    const float* y0 = Yp0 + (size_t)row * DIM;
    const float* y1 = Yp1 + (size_t)row * DIM;

    float v[4];
    float s = 0.f, s2 = 0.f;
#pragma unroll
    for (int e = 0; e < 4; ++e) {
        const int idx = threadIdx.x + e * 256;
        v[e] = y0[idx] + y1[idx];
        s += v[e];
        s2 += v[e] * v[e];
    }
#pragma unroll
    for (int off = 1; off < 64; off <<= 1) {
        s  += __shfl_xor(s, off);
        s2 += __shfl_xor(s2, off);
    }
    __shared__ float ps[4], ps2[4];
    const int wave = threadIdx.x >> 6;
    if ((threadIdx.x & 63) == 0) { ps[wave] = s; ps2[wave] = s2; }
    __syncthreads();
    s  = ps[0] + ps[1] + ps[2] + ps[3];
    s2 = ps2[0] + ps2[1] + ps2[2] + ps2[3];

    const float mu   = s * (1.0f / DIM);
    const float var  = s2 * (1.0f / DIM) - mu * mu;
    const float rstd = rsqrtf(var + 1e-5f);

#pragma unroll
    for (int e = 0; e < 4; ++e) {
        const int idx = threadIdx.x + e * 256;
        out[(size_t)row * DIM + idx] =
            (v[e] - mu) * rstd * gamma[idx] + beta[idx];
    }
}

// ---------------------------------------------------------------------------
extern "C" void kernel_launch(void* const* d_in, const int* in_sizes, int n_in,
                              void* d_out, int out_size, void* d_ws, size_t ws_size,
                              hipStream_t stream)
{
    const float* x     = (const float*)d_in[0];
    const float* Wq    = (const float*)d_in[1];
    const float* bq    = (const float*)d_in[2];
    const float* Wk    = (const float*)d_in[3];
    const float* bk    = (const float*)d_in[4];
    const float* Wv    = (const float*)d_in[5];
    const float* bv    = (const float*)d_in[6];
    const float* Wo    = (const float*)d_in[7];
    const float* bo    = (const float*)d_in[8];
    const float* alpha = (const float*)d_in[9];
    const float* phi   = (const float*)d_in[10];
    const float* temp  = (const float*)d_in[11];
    const float* gamma = (const float*)d_in[12];
    const float* beta  = (const float*)d_in[13];

    float* out = (float*)d_out;

    const int B = 2;
    const int M = B * SEQ;                 // 2048

    // ws layout (MB):
    //   [0,4)   xb    [4,6) Wqb   [6,8) Wkb   [8,10) Wvb   [10,12) Wob
    //   [12,16) Qb    [16,20) Kb  [20,24) Vb  [24,28) AO
    //   Yp0 (fp32 8MB) aliases [0,8)  — xb/Wqb/Wkb dead by O-proj
    //   Yp1 (fp32 8MB) aliases [12,20) — Qb/Kb dead by O-proj
    char* wsb = (char*)d_ws;
    __hip_bfloat16* xb  = (__hip_bfloat16*)(wsb + 0);
    __hip_bfloat16* Wqb = (__hip_bfloat16*)(wsb + (4u  << 20));
    __hip_bfloat16* Wkb = (__hip_bfloat16*)(wsb + (6u  << 20));
    __hip_bfloat16* Wvb = (__hip_bfloat16*)(wsb + (8u  << 20));
    __hip_bfloat16* Wob = (__hip_bfloat16*)(wsb + (10u << 20));
    __hip_bfloat16* Qb  = (__hip_bfloat16*)(wsb + (12u << 20));
    __hip_bfloat16* Kb  = (__hip_bfloat16*)(wsb + (16u << 20));
    __hip_bfloat16* Vb  = (__hip_bfloat16*)(wsb + (20u << 20));
    __hip_bfloat16* AO  = (__hip_bfloat16*)(wsb + (24u << 20));
    float*          Yp0 = (float*)(wsb + 0);
    float*          Yp1 = (float*)(wsb + (12u << 20));

    hipLaunchKernelGGL(cvt_all, dim3(2048, 5), dim3(256), 0, stream,
                       x, Wq, Wk, Wv, Wo, xb, Wqb, Wkb, Wvb, Wob);

    hipLaunchKernelGGL(gemm_qkv, dim3(M / 64, DIM / 128, 3), dim3(256), 0, stream,
                       xb, Wqb, Wkb, Wvb, bq, bk, bv, Qb, Kb, Vb, M, DIM, DIM);

    hipLaunchKernelGGL(attn_kernel, dim3(SEQ / 32, B * NH), dim3(256), 0, stream,
                       Qb, Kb, Vb, alpha, phi, temp, AO);

    hipLaunchKernelGGL(gemm_osplit, dim3(M / 64, DIM / 128, 2), dim3(256), 0, stream,
                       AO, Wob, bo, Yp0, Yp1, M, DIM, DIM);

    hipLaunchKernelGGL(ln_kernel, dim3(M), dim3(256), 0, stream,
                       Yp0, Yp1, gamma, beta, out);
}